// Round 9
// baseline (21.295 us; speedup 1.0000x reference)
//
#include <hip/hip_runtime.h>

// Problem constants (from reference)
#define N_ 16
#define A_ 4096
#define G_ 256
#define C_ 80
#define BIG_ 1e8f
#define LN2_ 0.69314718055994531f

// ROUND 9 = DIAGNOSTIC ABLATION #3 (correctness-preserving).
// Base = round 4 EXACT structure (calibrated: 15.31us, argmin=3.83,
// focal=2.83, residual R=8.65). This round repeats the per-pass GLOBAL LOAD
// phase (pb, qb, 5 logits, and the dependent xt) LREPEAT_ times through
// asm-laundered pointers: compiler must emit fresh loads each repeat; loaded
// values kept live; last repeat feeds the real compute -> output identical.
// dur = 15.31 + (LREPEAT_-1)*4*l_warm  ->  l_warm = (dur-15.31)/20.
#define LREPEAT_ 6

__global__ __launch_bounds__(256, 4) void cbppl_fused_kernel(
    const float* __restrict__ gt_padded,    // (N, G, 4)
    const float* __restrict__ prop_boxes,   // (N, A, 4)
    const float* __restrict__ pred_boxes,   // (N, A, 4)
    const float* __restrict__ class_logits, // (N, A, C)
    const int*   __restrict__ gt_masks,     // (N, G) bool->int32
    const int*   __restrict__ gt_classes,   // (N, G)
    float* __restrict__ out_cls,            // (N, A)
    float* __restrict__ out_proj)           // (N, A)
{
    __shared__ float4 s_gt[G_];
    __shared__ int    s_cls[G_];

    const int t   = threadIdx.x;
    const int sub = t & 15;                 // lane-in-group
    const int n   = blockIdx.x >> 6;        // 64 blocks per batch
    const int ab  = (blockIdx.x & 63) << 6; // 64 anchors per block

    // ---- one-time: stage masked gt boxes + classes to LDS ----
    {
        const int gidx = n * G_ + t;        // t == g (256 threads)
        float4 g4 = ((const float4*)gt_padded)[gidx];
        if (!gt_masks[gidx]) { g4.x = BIG_; g4.y = BIG_; g4.z = BIG_; g4.w = BIG_; }
        s_gt[t]  = g4;
        s_cls[t] = gt_classes[gidx];
    }
    __syncthreads();

    // ---- one-time: register-cache 16 boxes per lane (interleaved) ----
    float4 b[16];
    #pragma unroll
    for (int m = 0; m < 16; ++m) b[m] = s_gt[sub + (m << 4)];

    // ---- 4 passes: 4 anchors per pass (one per 16-lane group) ----
    #pragma unroll 1
    for (int p = 0; p < 4; ++p) {
        const int ai  = ((t >> 6) << 4) + (p << 2) + ((t >> 4) & 3);
        const int row = n * A_ + ab + ai;

        // ======== ABLATION: per-pass load phase repeated LREPEAT_ times ====
        const unsigned long long pb_addr =
            (unsigned long long)&((const float4*)prop_boxes)[row];
        const unsigned long long qb_addr =
            (unsigned long long)&((const float4*)pred_boxes)[row];
        const unsigned long long lr_addr =
            (unsigned long long)(class_logits + (size_t)row * C_);

        float4 pb, qb;
        float  xv[5];
        #pragma unroll
        for (int rep = 0; rep < LREPEAT_; ++rep) {
            unsigned long long pa = pb_addr, qa = qb_addr, la = lr_addr;
            asm volatile("" : "+v"(pa), "+v"(qa), "+v"(la));   // fresh pointers
            const float4* p_ = (const float4*)pa;
            const float4* q_ = (const float4*)qa;
            const float*  l_ = (const float*)la;
            pb = *p_;
            qb = *q_;
            #pragma unroll
            for (int k = 0; k < 5; ++k) xv[k] = l_[sub + (k << 4)];
            asm volatile("" :: "v"(pb.x), "v"(pb.y), "v"(pb.z), "v"(pb.w),
                               "v"(qb.x), "v"(qb.y), "v"(qb.z), "v"(qb.w),
                               "v"(xv[0]), "v"(xv[1]), "v"(xv[2]),
                               "v"(xv[3]), "v"(xv[4]));        // keep live
        }
        const float* lrow = (const float*)lr_addr;
        // ===================================================================

        // local argmin over this lane's 16 register boxes
        float dloc = INFINITY;
        int   mloc = 0;
        #pragma unroll
        for (int m = 0; m < 16; ++m) {
            const float d = fabsf(pb.x - b[m].x) + fabsf(pb.y - b[m].y)
                          + fabsf(pb.z - b[m].z) + fabsf(pb.w - b[m].w);
            if (d < dloc) { dloc = d; mloc = m; }  // lower m = lower g
        }
        const int iloc = (mloc << 4) + sub;        // g index

        // 16-lane group argmin: min(d), then min index among tied lanes
        float dmin = dloc;
        #pragma unroll
        for (int k = 1; k < 16; k <<= 1) dmin = fminf(dmin, __shfl_xor(dmin, k, 64));
        int cand = (dloc == dmin) ? iloc : 0x7FFFFFFF;
        #pragma unroll
        for (int k = 1; k < 16; k <<= 1) cand = min(cand, __shfl_xor(cand, k, 64));
        const int closest  = cand;
        const int nonempty = (dmin < BIG_);

        // epilogue lookups: uniform per group -> LDS broadcast
        const float4 cb     = s_gt[closest];
        const int    target = s_cls[closest];
        const float  pd = fabsf(qb.x - cb.x) + fabsf(qb.y - cb.y)
                        + fabsf(qb.z - cb.z) + fabsf(qb.w - cb.w);

        // ==== ABLATION: dependent broadcast load repeated LREPEAT_ times ===
        float xt;
        #pragma unroll
        for (int rep = 0; rep < LREPEAT_; ++rep) {
            unsigned long long la = lr_addr;
            asm volatile("" : "+v"(la));
            xt = ((const float*)la)[target];
            asm volatile("" :: "v"(xt));
        }
        // ===================================================================

        // focal loss, negative-class closed form: 0.75 * softplus(x) * p^2
        float acc = 0.0f;
        #pragma unroll
        for (int k = 0; k < 5; ++k) {
            const float x  = xv[k];
            const float e  = __expf(-fabsf(x));
            const float tt = 1.0f + e;
            const float sp = fmaf(LN2_, __log2f(tt), fmaxf(x, 0.0f)); // softplus
            const float r  = __builtin_amdgcn_rcpf(tt);
            const float pp = (x >= 0.0f) ? r : e * r;                 // sigmoid
            acc += sp * pp * pp;
        }
        acc *= 0.75f;

        // single target-class correction (owner lane adds)
        {
            const float e  = __expf(-fabsf(xt));
            const float tt = 1.0f + e;
            const float sp = fmaf(LN2_, __log2f(tt), fmaxf(xt, 0.0f));
            const float r  = __builtin_amdgcn_rcpf(tt);
            const float pp = (xt >= 0.0f) ? r : e * r;
            const float q  = 1.0f - pp;
            const float corr = 0.25f * (sp - xt) * q * q - 0.75f * sp * pp * pp;
            if ((target & 15) == sub) acc += corr;
        }

        // group sum of focal partials
        #pragma unroll
        for (int k = 1; k < 16; k <<= 1) acc += __shfl_xor(acc, k, 64);

        if (sub == 0) {
            out_cls[row]  = nonempty ? acc * (1.0f / (float)C_) : 0.0f;
            out_proj[row] = nonempty ? pd : 0.0f;
        }
    }
}

extern "C" void kernel_launch(void* const* d_in, const int* in_sizes, int n_in,
                              void* d_out, int out_size, void* d_ws, size_t ws_size,
                              hipStream_t stream) {
    const float* gt_padded    = (const float*)d_in[0];
    const float* prop_boxes   = (const float*)d_in[1];
    const float* pred_boxes   = (const float*)d_in[2];
    const float* class_logits = (const float*)d_in[3];
    const int*   gt_masks     = (const int*)d_in[4];
    const int*   gt_classes   = (const int*)d_in[5];

    float* out = (float*)d_out;
    float* out_cls  = out;             // classification_loss, (N, A)
    float* out_proj = out + N_ * A_;   // projection_loss,     (N, A)

    dim3 grid(N_ * A_ / 64);           // 1024 blocks, 64 anchors each
    dim3 block(256);
    cbppl_fused_kernel<<<grid, block, 0, stream>>>(
        gt_padded, prop_boxes, pred_boxes, class_logits,
        gt_masks, gt_classes, out_cls, out_proj);
}

// Round 10
// 14.843 us; speedup vs baseline: 1.4347x; 1.4347x over previous
//
#include <hip/hip_runtime.h>

// Problem constants (from reference)
#define N_ 16
#define A_ 4096
#define G_ 256
#define C_ 80
#define BIG_ 1e8f
#define LN2_ 0.69314718055994531f

// Round 10: cross-lane reductions moved from ds_swizzle (__shfl_xor, LDS
// pipe, ~60cyc/stage serial) to DPP (VALU pipe, ~4cyc/stage).
// 16-lane butterfly = xor1 (quad_perm 1,0,3,2), xor2 (quad_perm 2,3,0,1),
// xor7 (row_half_mirror), xor15 (row_mirror). Also: no dependent x_target
// load (register cndmask select, bit-exact per round 8) and branchless focal
// (exact identities, absmax was 0.0 in round 8). Base structure = round 4.

#define DPP_XOR1  0xB1   // quad_perm(1,0,3,2)
#define DPP_XOR2  0x4E   // quad_perm(2,3,0,1)
#define DPP_XOR7  0x141  // row_half_mirror: i -> 7-i = i^7 within 8
#define DPP_XOR15 0x140  // row_mirror:      i -> 15-i = i^15 within 16

template<int CTRL>
__device__ __forceinline__ float dppf(float x) {
    return __int_as_float(__builtin_amdgcn_update_dpp(
        0, __float_as_int(x), CTRL, 0xF, 0xF, true));
}
template<int CTRL>
__device__ __forceinline__ int dppi(int x) {
    return __builtin_amdgcn_update_dpp(0, x, CTRL, 0xF, 0xF, true);
}

// one lexicographic-(d, idx) argmin butterfly stage over a DPP pairing
template<int CTRL>
__device__ __forceinline__ void argmin_stage(float& d, int& idx) {
    const float od = dppf<CTRL>(d);
    const int   oc = dppi<CTRL>(idx);
    const bool  bt = (od < d) || (od == d && oc < idx);
    d   = bt ? od : d;
    idx = bt ? oc : idx;
}

__global__ __launch_bounds__(256, 4) void cbppl_fused_kernel(
    const float* __restrict__ gt_padded,    // (N, G, 4)
    const float* __restrict__ prop_boxes,   // (N, A, 4)
    const float* __restrict__ pred_boxes,   // (N, A, 4)
    const float* __restrict__ class_logits, // (N, A, C)
    const int*   __restrict__ gt_masks,     // (N, G) bool->int32
    const int*   __restrict__ gt_classes,   // (N, G)
    float* __restrict__ out_cls,            // (N, A)
    float* __restrict__ out_proj)           // (N, A)
{
    __shared__ float4 s_gt[G_];
    __shared__ int    s_cls[G_];

    const int t   = threadIdx.x;
    const int sub = t & 15;                 // lane-in-group
    const int n   = blockIdx.x >> 6;        // 64 blocks per batch
    const int ab  = (blockIdx.x & 63) << 6; // 64 anchors per block

    // ---- one-time: stage masked gt boxes + classes to LDS ----
    {
        const int gidx = n * G_ + t;        // t == g (256 threads)
        float4 g4 = ((const float4*)gt_padded)[gidx];
        if (!gt_masks[gidx]) { g4.x = BIG_; g4.y = BIG_; g4.z = BIG_; g4.w = BIG_; }
        s_gt[t]  = g4;
        s_cls[t] = gt_classes[gidx];
    }
    __syncthreads();

    // ---- one-time: register-cache 16 boxes per lane (interleaved) ----
    float4 b[16];
    #pragma unroll
    for (int m = 0; m < 16; ++m) b[m] = s_gt[sub + (m << 4)];

    // ---- 4 passes: 4 anchors per pass (one per 16-lane group) ----
    for (int p = 0; p < 4; ++p) {
        const int ai  = ((t >> 6) << 4) + (p << 2) + ((t >> 4) & 3);
        const int row = n * A_ + ab + ai;

        const float4 pb = ((const float4*)prop_boxes)[row];   // group-broadcast
        const float4 qb = ((const float4*)pred_boxes)[row];

        // 5 logit loads issued early (independent of argmin)
        const float* lrow = class_logits + (size_t)row * C_;
        float xv[5];
        #pragma unroll
        for (int k = 0; k < 5; ++k) xv[k] = lrow[sub + (k << 4)];

        // local argmin over this lane's 16 register boxes
        float dloc = INFINITY;
        int   mloc = 0;
        #pragma unroll
        for (int m = 0; m < 16; ++m) {
            const float d = fabsf(pb.x - b[m].x) + fabsf(pb.y - b[m].y)
                          + fabsf(pb.z - b[m].z) + fabsf(pb.w - b[m].w);
            if (d < dloc) { dloc = d; mloc = m; }  // lower m = lower g
        }
        int iloc = (mloc << 4) + sub;              // g index

        // 16-lane argmin butterfly on DPP (VALU pipe, no LDS):
        // lexicographic (d, idx) min => global min-d, smallest g among ties
        argmin_stage<DPP_XOR1 >(dloc, iloc);
        argmin_stage<DPP_XOR2 >(dloc, iloc);
        argmin_stage<DPP_XOR7 >(dloc, iloc);
        argmin_stage<DPP_XOR15>(dloc, iloc);
        const int   closest  = iloc;
        const int   nonempty = (dloc < BIG_);

        // epilogue lookups: uniform per group -> LDS broadcast
        const float4 cb     = s_gt[closest];
        const int    target = s_cls[closest];
        const float  pd = fabsf(qb.x - cb.x) + fabsf(qb.y - cb.y)
                        + fabsf(qb.z - cb.z) + fabsf(qb.w - cb.w);

        // focal, negative-class closed form (branchless; exact identities):
        //   u = e^-x;  p = 1/(1+u);  softplus = x + ln2*log2(1+u)
        float acc = 0.0f;
        #pragma unroll
        for (int j = 0; j < 5; ++j) {
            const float x  = xv[j];
            const float u  = __expf(-x);
            const float tt = 1.0f + u;
            const float sp = fmaf(LN2_, __log2f(tt), x);
            const float r  = __builtin_amdgcn_rcpf(tt);
            acc = fmaf(sp, r * r, acc);
        }
        acc *= 0.75f;

        // target-class correction; xt selected from registers (kt uniform)
        {
            const int kt = target >> 4;
            float xt = xv[0];
            xt = (kt == 1) ? xv[1] : xt;
            xt = (kt == 2) ? xv[2] : xt;
            xt = (kt == 3) ? xv[3] : xt;
            xt = (kt == 4) ? xv[4] : xt;
            const float u  = __expf(-xt);
            const float tt = 1.0f + u;
            const float sp = fmaf(LN2_, __log2f(tt), xt);
            const float pp = __builtin_amdgcn_rcpf(tt);
            const float q  = 1.0f - pp;
            const float corr = fmaf(0.25f * (sp - xt), q * q,
                                    -0.75f * sp * pp * pp);
            acc += ((target & 15) == sub) ? corr : 0.0f;  // owner lane adds
        }

        // group sum of focal partials on DPP
        acc += dppf<DPP_XOR1 >(acc);
        acc += dppf<DPP_XOR2 >(acc);
        acc += dppf<DPP_XOR7 >(acc);
        acc += dppf<DPP_XOR15>(acc);

        if (sub == 0) {
            out_cls[row]  = nonempty ? acc * (1.0f / (float)C_) : 0.0f;
            out_proj[row] = nonempty ? pd : 0.0f;
        }
    }
}

extern "C" void kernel_launch(void* const* d_in, const int* in_sizes, int n_in,
                              void* d_out, int out_size, void* d_ws, size_t ws_size,
                              hipStream_t stream) {
    const float* gt_padded    = (const float*)d_in[0];
    const float* prop_boxes   = (const float*)d_in[1];
    const float* pred_boxes   = (const float*)d_in[2];
    const float* class_logits = (const float*)d_in[3];
    const int*   gt_masks     = (const int*)d_in[4];
    const int*   gt_classes   = (const int*)d_in[5];

    float* out = (float*)d_out;
    float* out_cls  = out;             // classification_loss, (N, A)
    float* out_proj = out + N_ * A_;   // projection_loss,     (N, A)

    dim3 grid(N_ * A_ / 64);           // 1024 blocks, 64 anchors each
    dim3 block(256);
    cbppl_fused_kernel<<<grid, block, 0, stream>>>(
        gt_padded, prop_boxes, pred_boxes, class_logits,
        gt_masks, gt_classes, out_cls, out_proj);
}